// Round 3
// baseline (105.785 us; speedup 1.0000x reference)
//
#include <hip/hip_runtime.h>

constexpr int NL = 32;    // layers
constexpr int PPT = 8;    // points per thread

// Degree-13 odd polynomial approximation of tanh on [-3.4, 3.4], clamped
// (saturation err 1-tanh(3.4)=0.0019; poly err <= ~0.0023, verified at
// off-node points s=1,2,4,9). NO transcendentals: v_exp/v_rcp are 1/8-rate
// (~16 cyc/wave-inst) on gfx950; this replaces 36 cyc/activation with ~20.
__device__ __forceinline__ float tanh_poly(float x) {
#if __has_builtin(__builtin_amdgcn_fmed3f)
    float t = __builtin_amdgcn_fmed3f(x, -3.4f, 3.4f);
#else
    float t = fminf(fmaxf(x, -3.4f), 3.4f);
#endif
    float s = t * t;
    float u = fmaf(s, 2.3524e-06f, -1.000059e-04f);
    u = fmaf(s, u, 1.7302740e-03f);
    u = fmaf(s, u, -1.5874717e-02f);
    u = fmaf(s, u, 8.5976700e-02f);
    u = fmaf(s, u, -3.0595090e-01f);
    u = fmaf(s, u, 9.9691910e-01f);
    return t * u;   // odd: t * poly(t^2)
}

// Table layout per layer i (16 floats), natural scale:
//  [0..6]  forward:  m00,m01,m10,m11, C0=(M·b).x, C1=(M·b).y, T=+aw
//  [8..14] inverse:  i00,i01,i10,i11, D0=-b0, D1=-b1, U=-aw
__global__ void build_tables(const float* __restrict__ act_w,
                             const float* __restrict__ bias_b,
                             const float* __restrict__ lin_w,
                             float* __restrict__ tab)
{
    int t = threadIdx.x;
    if (t >= NL) return;
    // Compose the 8 unit shears into M (det = 1).
    float m00 = 1.f, m01 = 0.f, m10 = 0.f, m11 = 1.f;
    #pragma unroll
    for (int j = 0; j < 8; ++j) {
        float w = lin_w[t * 8 + j];
        if ((j & 1) == 0) { m00 = fmaf(w, m10, m00); m01 = fmaf(w, m11, m01); }
        else              { m10 = fmaf(w, m00, m10); m11 = fmaf(w, m01, m11); }
    }
    float b0 = bias_b[2 * t], b1 = bias_b[2 * t + 1];
    float aw = act_w[t];
    float* f = &tab[t * 16];
    // forward: v <- M*(v_act + b) = M*v_act + M*b
    f[0] = m00; f[1] = m01; f[2] = m10; f[3] = m11;
    f[4] = fmaf(m00, b0, m01 * b1);
    f[5] = fmaf(m10, b0, m11 * b1);
    f[6] = aw; f[7] = 0.f;
    // inverse: v <- Minv*v - b, then subtract activation
    f[8]  = m11; f[9]  = -m01; f[10] = -m10; f[11] = m00;
    f[12] = -b0; f[13] = -b1; f[14] = -aw; f[15] = 0.f;
}

__global__ __launch_bounds__(256) void sympnet_main(
    const float* __restrict__ x,
    const float* __restrict__ tab,
    float* __restrict__ out)
{
    int gid = blockIdx.x * blockDim.x + threadIdx.x;
    const float4* x4 = (const float4*)x;
    float4* out4 = (float4*)out;
    long base = (long)gid * (PPT / 2);

    float Q[PPT], P[PPT];
    #pragma unroll
    for (int k = 0; k < PPT / 2; ++k) {
        float4 v = x4[base + k];
        Q[2*k]   = v.x; P[2*k]   = v.y;
        Q[2*k+1] = v.z; P[2*k+1] = v.w;
    }

    // ---------------- forward chain (2 layers / iter) ----------------
    #pragma unroll 1
    for (int i = 0; i < NL; i += 2) {
        const float* f = &tab[i * 16];           // even layer: q += aw*tanh(p)
        float m00=f[0], m01=f[1], m10=f[2], m11=f[3], C0=f[4], C1=f[5], T=f[6];
        const float* g = &tab[(i + 1) * 16];     // odd layer:  p += aw*tanh(q)
        float n00=g[0], n01=g[1], n10=g[2], n11=g[3], E0=g[4], E1=g[5], U=g[6];
        #pragma unroll
        for (int k = 0; k < PPT; ++k) {
            float Qa = fmaf(T, tanh_poly(P[k]), Q[k]);
            float Qn = fmaf(m00, Qa, fmaf(m01, P[k], C0));
            float Pn = fmaf(m10, Qa, fmaf(m11, P[k], C1));
            float Pa = fmaf(U, tanh_poly(Qn), Pn);
            Q[k] = fmaf(n00, Qn, fmaf(n01, Pa, E0));
            P[k] = fmaf(n10, Qn, fmaf(n11, Pa, E1));
        }
    }

    // time reversal
    #pragma unroll
    for (int k = 0; k < PPT; ++k) P[k] = -P[k];

    // ---------------- inverse chain (2 layers / iter) ----------------
    #pragma unroll 1
    for (int i = NL - 1; i > 0; i -= 2) {
        const float* g = &tab[i * 16 + 8];       // odd layer inverse: p -= aw*tanh(q)
        float n00=g[0], n01=g[1], n10=g[2], n11=g[3], E0=g[4], E1=g[5], U=g[6];
        const float* f = &tab[(i - 1) * 16 + 8]; // even layer inverse: q -= aw*tanh(p)
        float m00=f[0], m01=f[1], m10=f[2], m11=f[3], C0=f[4], C1=f[5], T=f[6];
        #pragma unroll
        for (int k = 0; k < PPT; ++k) {
            float Qn = fmaf(n00, Q[k], fmaf(n01, P[k], E0));
            float Pn = fmaf(n10, Q[k], fmaf(n11, P[k], E1));
            Pn = fmaf(U, tanh_poly(Qn), Pn);             // U = -aw
            float Q2 = fmaf(m00, Qn, fmaf(m01, Pn, C0));
            float P2 = fmaf(m10, Qn, fmaf(m11, Pn, C1));
            Q[k] = fmaf(T, tanh_poly(P2), Q2);           // T = -aw
            P[k] = P2;
        }
    }

    // final scale [1, -1]
    #pragma unroll
    for (int k = 0; k < PPT / 2; ++k) {
        float4 o;
        o.x = Q[2*k];   o.y = -P[2*k];
        o.z = Q[2*k+1]; o.w = -P[2*k+1];
        out4[base + k] = o;
    }
}

extern "C" void kernel_launch(void* const* d_in, const int* in_sizes, int n_in,
                              void* d_out, int out_size, void* d_ws, size_t ws_size,
                              hipStream_t stream) {
    const float* x      = (const float*)d_in[0];
    const float* act_w  = (const float*)d_in[1];
    const float* bias_b = (const float*)d_in[2];
    const float* lin_w  = (const float*)d_in[3];
    float* out = (float*)d_out;
    float* tab = (float*)d_ws;   // NL*16 floats = 2 KB

    build_tables<<<1, 64, 0, stream>>>(act_w, bias_b, lin_w, tab);

    int npts = in_sizes[0] / 2;                    // 2097152
    int nthreads = npts / PPT;                     // 262144
    int blocks = (nthreads + 255) / 256;           // 1024
    sympnet_main<<<blocks, 256, 0, stream>>>(x, tab, out);
}

// Round 4
// 105.433 us; speedup vs baseline: 1.0033x; 1.0033x over previous
//
#include <hip/hip_runtime.h>

constexpr int NL = 32;    // layers
constexpr int PPT = 4;    // points per thread (2 x v2f pairs)

typedef float v2f __attribute__((ext_vector_type(2)));

__device__ __forceinline__ v2f splat(float a) { v2f r; r.x = a; r.y = a; return r; }
__device__ __forceinline__ v2f fma2(v2f a, v2f b, v2f c) { return __builtin_elementwise_fma(a, b, c); }
__device__ __forceinline__ v2f sfma(float s, v2f b, v2f c) { return __builtin_elementwise_fma(splat(s), b, c); }

// Degree-13 odd minimax-ish tanh on [-3.4,3.4], clamped. 9 packed ops for 2
// points. No transcendentals (v_exp/v_rcp are ~16cyc/wave-inst on gfx950).
__device__ __forceinline__ v2f tanh_poly2(v2f x) {
    v2f t = __builtin_elementwise_min(__builtin_elementwise_max(x, splat(-3.4f)), splat(3.4f));
    v2f s = t * t;
    v2f u = fma2(s, splat(2.3524e-06f), splat(-1.000059e-04f));
    u = fma2(s, u, splat(1.7302740e-03f));
    u = fma2(s, u, splat(-1.5874717e-02f));
    u = fma2(s, u, splat(8.5976700e-02f));
    u = fma2(s, u, splat(-3.0595090e-01f));
    u = fma2(s, u, splat(9.9691910e-01f));
    return t * u;
}

// Table layout per layer i (16 floats), natural scale:
//  [0..6]  forward:  m00,m01,m10,m11, C0=(M·b).x, C1=(M·b).y, T=+aw
//  [8..14] inverse:  i00,i01,i10,i11, D0=-b0, D1=-b1, U=-aw
__global__ void build_tables(const float* __restrict__ act_w,
                             const float* __restrict__ bias_b,
                             const float* __restrict__ lin_w,
                             float* __restrict__ tab)
{
    int t = threadIdx.x;
    if (t >= NL) return;
    float m00 = 1.f, m01 = 0.f, m10 = 0.f, m11 = 1.f;
    #pragma unroll
    for (int j = 0; j < 8; ++j) {
        float w = lin_w[t * 8 + j];
        if ((j & 1) == 0) { m00 = fmaf(w, m10, m00); m01 = fmaf(w, m11, m01); }
        else              { m10 = fmaf(w, m00, m10); m11 = fmaf(w, m01, m11); }
    }
    float b0 = bias_b[2 * t], b1 = bias_b[2 * t + 1];
    float aw = act_w[t];
    float* f = &tab[t * 16];
    f[0] = m00; f[1] = m01; f[2] = m10; f[3] = m11;
    f[4] = fmaf(m00, b0, m01 * b1);
    f[5] = fmaf(m10, b0, m11 * b1);
    f[6] = aw; f[7] = 0.f;
    f[8]  = m11; f[9]  = -m01; f[10] = -m10; f[11] = m00;
    f[12] = -b0; f[13] = -b1; f[14] = -aw; f[15] = 0.f;
}

__global__ __launch_bounds__(256) void sympnet_main(
    const float* __restrict__ x,
    const float* __restrict__ tab,
    float* __restrict__ out)
{
    int gid = blockIdx.x * blockDim.x + threadIdx.x;
    const float4* x4 = (const float4*)x;
    float4* out4 = (float4*)out;
    long base = (long)gid * (PPT / 2);

    v2f Q[PPT / 2], P[PPT / 2];
    #pragma unroll
    for (int k = 0; k < PPT / 2; ++k) {
        float4 v = x4[base + k];
        Q[k].x = v.x; P[k].x = v.y;   // point 2k
        Q[k].y = v.z; P[k].y = v.w;   // point 2k+1
    }

    // ---------------- forward chain (2 layers / iter) ----------------
    #pragma unroll 1
    for (int i = 0; i < NL; i += 2) {
        const float* f = &tab[i * 16];           // even layer: q += aw*tanh(p)
        float m00=f[0], m01=f[1], m10=f[2], m11=f[3], C0=f[4], C1=f[5], T=f[6];
        const float* g = &tab[(i + 1) * 16];     // odd layer:  p += aw*tanh(q)
        float n00=g[0], n01=g[1], n10=g[2], n11=g[3], E0=g[4], E1=g[5], U=g[6];
        #pragma unroll
        for (int k = 0; k < PPT / 2; ++k) {
            v2f Qa = sfma(T, tanh_poly2(P[k]), Q[k]);
            v2f Qn = sfma(m00, Qa, sfma(m01, P[k], splat(C0)));
            v2f Pn = sfma(m10, Qa, sfma(m11, P[k], splat(C1)));
            v2f Pa = sfma(U, tanh_poly2(Qn), Pn);
            Q[k] = sfma(n00, Qn, sfma(n01, Pa, splat(E0)));
            P[k] = sfma(n10, Qn, sfma(n11, Pa, splat(E1)));
        }
    }

    // time reversal
    #pragma unroll
    for (int k = 0; k < PPT / 2; ++k) P[k] = -P[k];

    // ---------------- inverse chain (2 layers / iter) ----------------
    #pragma unroll 1
    for (int i = NL - 1; i > 0; i -= 2) {
        const float* g = &tab[i * 16 + 8];       // odd layer inverse: p -= aw*tanh(q)
        float n00=g[0], n01=g[1], n10=g[2], n11=g[3], E0=g[4], E1=g[5], U=g[6];
        const float* f = &tab[(i - 1) * 16 + 8]; // even layer inverse: q -= aw*tanh(p)
        float m00=f[0], m01=f[1], m10=f[2], m11=f[3], C0=f[4], C1=f[5], T=f[6];
        #pragma unroll
        for (int k = 0; k < PPT / 2; ++k) {
            v2f Qn = sfma(n00, Q[k], sfma(n01, P[k], splat(E0)));
            v2f Pn = sfma(n10, Q[k], sfma(n11, P[k], splat(E1)));
            Pn = sfma(U, tanh_poly2(Qn), Pn);             // U = -aw
            v2f Q2 = sfma(m00, Qn, sfma(m01, Pn, splat(C0)));
            v2f P2 = sfma(m10, Qn, sfma(m11, Pn, splat(C1)));
            Q[k] = sfma(T, tanh_poly2(P2), Q2);           // T = -aw
            P[k] = P2;
        }
    }

    // final scale [1, -1]
    #pragma unroll
    for (int k = 0; k < PPT / 2; ++k) {
        float4 o;
        o.x = Q[k].x; o.y = -P[k].x;
        o.z = Q[k].y; o.w = -P[k].y;
        out4[base + k] = o;
    }
}

extern "C" void kernel_launch(void* const* d_in, const int* in_sizes, int n_in,
                              void* d_out, int out_size, void* d_ws, size_t ws_size,
                              hipStream_t stream) {
    const float* x      = (const float*)d_in[0];
    const float* act_w  = (const float*)d_in[1];
    const float* bias_b = (const float*)d_in[2];
    const float* lin_w  = (const float*)d_in[3];
    float* out = (float*)d_out;
    float* tab = (float*)d_ws;   // NL*16 floats = 2 KB

    build_tables<<<1, 64, 0, stream>>>(act_w, bias_b, lin_w, tab);

    int npts = in_sizes[0] / 2;                    // 2097152
    int nthreads = npts / PPT;                     // 524288
    int blocks = (nthreads + 255) / 256;           // 2048
    sympnet_main<<<blocks, 256, 0, stream>>>(x, tab, out);
}